// Round 1
// baseline (557.972 us; speedup 1.0000x reference)
//
#include <hip/hip_runtime.h>
#include <math.h>

// Problem constants (fixed by the reference)
#define N_NODES 1024
#define BATCH   8
#define FEAT    128        // F == O
#define NDIR    3
#define NB      (N_NODES*BATCH)   // 8192
#define G3      384               // 3*O

// ---------------------------------------------------------------------------
// GEMM: C[M,384] = A[M,128] @ Wt[384,128]^T + bias[384]
// 64x64 tile, 256 threads, 4x4 micro-tile, K staged in 2 chunks of 64.
// LDS tiles stored K-major so the inner loop uses float4 (b128) LDS reads.
// ---------------------------------------------------------------------------
__global__ __launch_bounds__(256) void gemm_abt(
    const float* __restrict__ A, const float* __restrict__ Wt,
    const float* __restrict__ bias, float* __restrict__ C, int M)
{
    __shared__ float As[64*68];   // [k][row], pad 68 to break bank strides
    __shared__ float Ws[64*68];   // [k][col]
    const int t  = threadIdx.x;
    const int tx = t & 15, ty = t >> 4;
    const int r0 = blockIdx.x * 64;
    const int c0 = blockIdx.y * 64;

    float acc[4][4] = {};
    for (int k0 = 0; k0 < 128; k0 += 64) {
        const int low6 = t & 63;     // k for A-load / k for W-load
        const int hi   = t >> 6;     // 0..3
        #pragma unroll
        for (int i = 0; i < 16; ++i) {
            int rl = hi + i*4;
            As[low6*68 + rl] = A[(r0+rl)*128 + k0 + low6];
        }
        #pragma unroll
        for (int i = 0; i < 16; ++i) {
            int cl = hi + i*4;
            Ws[low6*68 + cl] = Wt[(c0+cl)*128 + k0 + low6];
        }
        __syncthreads();
        #pragma unroll
        for (int kk = 0; kk < 64; ++kk) {
            float4 a4 = *reinterpret_cast<const float4*>(&As[kk*68 + ty*4]);
            float4 b4 = *reinterpret_cast<const float4*>(&Ws[kk*68 + tx*4]);
            float av[4] = {a4.x, a4.y, a4.z, a4.w};
            float bv[4] = {b4.x, b4.y, b4.z, b4.w};
            #pragma unroll
            for (int i = 0; i < 4; ++i)
                #pragma unroll
                for (int j = 0; j < 4; ++j)
                    acc[i][j] += av[i] * bv[j];
        }
        __syncthreads();
    }
    #pragma unroll
    for (int i = 0; i < 4; ++i) {
        int r = r0 + ty*4 + i;
        #pragma unroll
        for (int j = 0; j < 4; ++j) {
            int c = c0 + tx*4 + j;
            C[r*G3 + c] = acc[i][j] + bias[c];
        }
    }
}

// ---------------------------------------------------------------------------
// Fused support + highway-t GEMM:
//   cols 0..383  : support[d= c>>7][b][n][o = c&127] = x @ W[l,d] + Bc[l,d]
//   cols 384..511: tbuf[r][o=c-384] = relu(x @ Wh[l] + Bh[l])
// x rows are r = n*8+b (x is [N,B,F] row-major). support stored [D,B,N,O].
// ---------------------------------------------------------------------------
__global__ __launch_bounds__(256) void k_sup_t(
    const float* __restrict__ X,
    const float* __restrict__ Wl,    // [3,128,128]
    const float* __restrict__ Bcl,   // [3,128]
    const float* __restrict__ Whl,   // [128,128]
    const float* __restrict__ Bhl,   // [128]
    float* __restrict__ support,     // [3,8,1024,128]
    float* __restrict__ tbuf)        // [8192,128]
{
    __shared__ float As[64*68];      // [k][row]
    __shared__ float Bs[64*68];      // [k][col]
    const int t  = threadIdx.x;
    const int tx = t & 15, ty = t >> 4;
    const int r0 = blockIdx.x * 64;
    const int c0 = blockIdx.y * 64;  // 0..448, each tile within one region

    float acc[4][4] = {};
    for (int k0 = 0; k0 < 128; k0 += 64) {
        const int low6 = t & 63;
        const int hi   = t >> 6;
        #pragma unroll
        for (int i = 0; i < 16; ++i) {
            int rl = hi + i*4;
            As[low6*68 + rl] = X[(r0+rl)*128 + k0 + low6];
        }
        #pragma unroll
        for (int i = 0; i < 16; ++i) {
            int kl = hi + i*4;
            int cg = c0 + low6;
            float v;
            if (cg < 384) {
                int d = cg >> 7, o = cg & 127;
                v = Wl[(d*128 + k0 + kl)*128 + o];
            } else {
                int o = cg - 384;
                v = Whl[(k0 + kl)*128 + o];
            }
            Bs[kl*68 + low6] = v;
        }
        __syncthreads();
        #pragma unroll
        for (int kk = 0; kk < 64; ++kk) {
            float4 a4 = *reinterpret_cast<const float4*>(&As[kk*68 + ty*4]);
            float4 b4 = *reinterpret_cast<const float4*>(&Bs[kk*68 + tx*4]);
            float av[4] = {a4.x, a4.y, a4.z, a4.w};
            float bv[4] = {b4.x, b4.y, b4.z, b4.w};
            #pragma unroll
            for (int i = 0; i < 4; ++i)
                #pragma unroll
                for (int j = 0; j < 4; ++j)
                    acc[i][j] += av[i] * bv[j];
        }
        __syncthreads();
    }
    #pragma unroll
    for (int i = 0; i < 4; ++i) {
        int r = r0 + ty*4 + i;
        int n = r >> 3, b = r & 7;
        #pragma unroll
        for (int j = 0; j < 4; ++j) {
            int cg = c0 + tx*4 + j;
            float v = acc[i][j];
            if (cg < 384) {
                int d = cg >> 7, o = cg & 127;
                support[((d*8 + b)*1024 + n)*128 + o] = v + Bcl[d*128 + o];
            } else {
                int o = cg - 384;
                tbuf[r*128 + o] = fmaxf(v + Bhl[o], 0.0f);
            }
        }
    }
}

// ---------------------------------------------------------------------------
// agg[z][m][o] = sum_n adj[z][m][n] * support[z][n][o],  z = d*8+b (24 GEMMs)
// M=1024, K=1024, N=128. 64x64 tile, K chunks of 32.
// ---------------------------------------------------------------------------
__global__ __launch_bounds__(256) void k_agg(
    const float* __restrict__ adj, const float* __restrict__ support,
    float* __restrict__ agg)
{
    __shared__ float As[32*68];   // [k][m]
    __shared__ float Bs[32*68];   // [k][o]
    const int t  = threadIdx.x;
    const int tx = t & 15, ty = t >> 4;
    const int m0 = blockIdx.x * 64;
    const int o0 = blockIdx.y * 64;
    const int z  = blockIdx.z;
    const float* Az = adj     + (size_t)z * 1024 * 1024;
    const float* Bz = support + (size_t)z * 1024 * 128;

    float acc[4][4] = {};
    for (int k0 = 0; k0 < 1024; k0 += 32) {
        {
            int kl = t & 31, ml = t >> 5;     // ml 0..7
            #pragma unroll
            for (int i = 0; i < 8; ++i) {
                int m = ml + i*8;
                As[kl*68 + m] = Az[(m0+m)*1024 + k0 + kl];
            }
            int ol = t & 63, kl2 = t >> 6;    // kl2 0..3
            #pragma unroll
            for (int i = 0; i < 8; ++i) {
                int k = kl2 + i*4;
                Bs[k*68 + ol] = Bz[(k0+k)*128 + o0 + ol];
            }
        }
        __syncthreads();
        #pragma unroll
        for (int kk = 0; kk < 32; ++kk) {
            float4 a4 = *reinterpret_cast<const float4*>(&As[kk*68 + ty*4]);
            float4 b4 = *reinterpret_cast<const float4*>(&Bs[kk*68 + tx*4]);
            float av[4] = {a4.x, a4.y, a4.z, a4.w};
            float bv[4] = {b4.x, b4.y, b4.z, b4.w};
            #pragma unroll
            for (int i = 0; i < 4; ++i)
                #pragma unroll
                for (int j = 0; j < 4; ++j)
                    acc[i][j] += av[i] * bv[j];
        }
        __syncthreads();
    }
    float* Cz = agg + (size_t)z * 1024 * 128;
    #pragma unroll
    for (int i = 0; i < 4; ++i)
        #pragma unroll
        for (int j = 0; j < 4; ++j)
            Cz[(m0 + ty*4 + i)*128 + o0 + tx*4 + j] = acc[i][j];
}

// ---------------------------------------------------------------------------
// GRU gates + sum over d + relu + highway blend (fully fused elementwise).
// gi: [3,8,1024,384], gh: [8192,384] (row r=n*8+b), X/tbuf/Xout: [8192,128]
// ---------------------------------------------------------------------------
__global__ __launch_bounds__(256) void k_gates(
    const float* __restrict__ gi, const float* __restrict__ gh,
    const float* __restrict__ X, const float* __restrict__ tbuf,
    float* __restrict__ Xout)
{
    int idx = blockIdx.x * 256 + threadIdx.x;   // 0 .. NB*128
    int r = idx >> 7, o = idx & 127;
    int n = r >> 3, b = r & 7;
    float h = X[idx];
    const float* ghr = gh + (size_t)r * G3;
    float g_r = ghr[o], g_z = ghr[128 + o], g_n = ghr[256 + o];
    float acc = 0.0f;
    #pragma unroll
    for (int d = 0; d < 3; ++d) {
        const float* gir = gi + (size_t)((d*8 + b)*1024 + n) * G3;
        float i_r = gir[o], i_z = gir[128 + o], i_n = gir[256 + o];
        float rg = 1.0f / (1.0f + expf(-(i_r + g_r)));
        float zg = 1.0f / (1.0f + expf(-(i_z + g_z)));
        float ng = tanhf(i_n + rg * g_n);
        acc += (1.0f - zg) * ng + zg * h;
    }
    float outv = fmaxf(acc, 0.0f);
    float tg = tbuf[idx];
    Xout[idx] = outv * tg + h * (1.0f - tg);
}

// ---------------------------------------------------------------------------
extern "C" void kernel_launch(void* const* d_in, const int* in_sizes, int n_in,
                              void* d_out, int out_size, void* d_ws, size_t ws_size,
                              hipStream_t stream) {
    const float* inputs = (const float*)d_in[0];   // [1024,8,128]
    const float* adj    = (const float*)d_in[1];   // [3,8,1024,1024]
    const float* W      = (const float*)d_in[2];   // [2,3,128,128]
    const float* Bc     = (const float*)d_in[3];   // [2,3,128]
    const float* Wh     = (const float*)d_in[4];   // [2,128,128]
    const float* Bh     = (const float*)d_in[5];   // [2,128]
    const float* Wih    = (const float*)d_in[6];   // [2,384,128]
    const float* Whh    = (const float*)d_in[7];   // [2,384,128]
    const float* bih    = (const float*)d_in[8];   // [2,384]
    const float* bhh    = (const float*)d_in[9];   // [2,384]

    float* ws = (float*)d_ws;
    float* x1      = ws;                      // 1,048,576
    float* support = x1      + 1048576;       // 3,145,728
    float* gh      = support + 3145728;       // 3,145,728
    float* tbuf    = gh      + 3145728;       // 1,048,576
    float* agg     = tbuf    + 1048576;       // 3,145,728
    float* gi      = agg     + 3145728;       // 9,437,184  (total 80 MB)

    for (int l = 0; l < 2; ++l) {
        const float* xin = (l == 0) ? inputs : x1;
        float* xout = (l == 1) ? (float*)d_out : x1;

        // support (3 dirs) + highway t
        k_sup_t<<<dim3(128, 8), dim3(256), 0, stream>>>(
            xin, W + l*3*128*128, Bc + l*3*128, Wh + l*128*128, Bh + l*128,
            support, tbuf);
        // gh = x @ Whh^T + bhh  (independent of d — computed once)
        gemm_abt<<<dim3(128, 6), dim3(256), 0, stream>>>(
            xin, Whh + l*G3*128, bhh + l*G3, gh, NB);
        // agg = adj @ support (24 batched GEMMs)
        k_agg<<<dim3(16, 2, 24), dim3(256), 0, stream>>>(adj, support, agg);
        // gi = agg @ Wih^T + bih
        gemm_abt<<<dim3(384, 6), dim3(256), 0, stream>>>(
            agg, Wih + l*G3*128, bih + l*G3, gi, 3*NB);
        // gates + sum_d + relu + highway
        k_gates<<<dim3(4096), dim3(256), 0, stream>>>(gi, gh, xin, tbuf, xout);
    }
}

// Round 2
// 394.767 us; speedup vs baseline: 1.4134x; 1.4134x over previous
//
#include <hip/hip_runtime.h>
#include <math.h>

// Problem constants (fixed by the reference)
#define N_NODES 1024
#define BATCH   8
#define FEAT    128        // F == O
#define NDIR    3
#define NB      (N_NODES*BATCH)   // 8192
#define G3      384               // 3*O

typedef __bf16 bf16_t;
using bf16x8 = __attribute__((ext_vector_type(8))) __bf16;
using bf16x4 = __attribute__((ext_vector_type(4))) __bf16;
using f32x4  = __attribute__((ext_vector_type(4))) float;

// async global->LDS 16B per lane; LDS dest must be wave-uniform base (+lane*16)
#define GLOAD_LDS16(g, l) \
    __builtin_amdgcn_global_load_lds((const __attribute__((address_space(1))) void*)(g), \
                                     (__attribute__((address_space(3))) void*)(l), 16, 0, 0)

// ---------------------------------------------------------------------------
// fp32 -> bf16 bulk convert (float4 in, 4x bf16 out)
// ---------------------------------------------------------------------------
__global__ __launch_bounds__(256) void k_cvt(
    const float* __restrict__ src, bf16_t* __restrict__ dst, int n4)
{
    int i = blockIdx.x * 256 + threadIdx.x;
    int stride = gridDim.x * 256;
    for (; i < n4; i += stride) {
        float4 v = reinterpret_cast<const float4*>(src)[i];
        bf16x4 o;
        o[0] = (bf16_t)v.x; o[1] = (bf16_t)v.y; o[2] = (bf16_t)v.z; o[3] = (bf16_t)v.w;
        *reinterpret_cast<bf16x4*>(&dst[(size_t)i * 4]) = o;
    }
}

// ---------------------------------------------------------------------------
// GEMM: gh[M,384] = A[M,128] @ Wt[384,128]^T + bias, output bf16.
// fp32 tiled (64x64, 4x4 micro-tile). M=8192.
// ---------------------------------------------------------------------------
__global__ __launch_bounds__(256) void gemm_abt(
    const float* __restrict__ A, const float* __restrict__ Wt,
    const float* __restrict__ bias, bf16_t* __restrict__ C, int M)
{
    __shared__ float As[64*68];
    __shared__ float Ws[64*68];
    const int t  = threadIdx.x;
    const int tx = t & 15, ty = t >> 4;
    const int r0 = blockIdx.x * 64;
    const int c0 = blockIdx.y * 64;

    float acc[4][4] = {};
    for (int k0 = 0; k0 < 128; k0 += 64) {
        const int low6 = t & 63;
        const int hi   = t >> 6;
        #pragma unroll
        for (int i = 0; i < 16; ++i) {
            int rl = hi + i*4;
            As[low6*68 + rl] = A[(r0+rl)*128 + k0 + low6];
        }
        #pragma unroll
        for (int i = 0; i < 16; ++i) {
            int cl = hi + i*4;
            Ws[low6*68 + cl] = Wt[(c0+cl)*128 + k0 + low6];
        }
        __syncthreads();
        #pragma unroll
        for (int kk = 0; kk < 64; ++kk) {
            float4 a4 = *reinterpret_cast<const float4*>(&As[kk*68 + ty*4]);
            float4 b4 = *reinterpret_cast<const float4*>(&Ws[kk*68 + tx*4]);
            float av[4] = {a4.x, a4.y, a4.z, a4.w};
            float bv[4] = {b4.x, b4.y, b4.z, b4.w};
            #pragma unroll
            for (int i = 0; i < 4; ++i)
                #pragma unroll
                for (int j = 0; j < 4; ++j)
                    acc[i][j] += av[i] * bv[j];
        }
        __syncthreads();
    }
    #pragma unroll
    for (int i = 0; i < 4; ++i) {
        int r = r0 + ty*4 + i;
        #pragma unroll
        for (int j = 0; j < 4; ++j) {
            int c = c0 + tx*4 + j;
            C[(size_t)r*G3 + c] = (bf16_t)(acc[i][j] + bias[c]);
        }
    }
}

// ---------------------------------------------------------------------------
// Fused support + highway-t GEMM (fp32 compute):
//   cols 0..383  : support_t[d*8+b][o][n] = bf16(x @ W[l,d] + Bc[l,d])  (TRANSPOSED)
//   cols 384..511: tbuf[r][o] = relu(x @ Wh[l] + Bh[l])   (fp32)
// ---------------------------------------------------------------------------
__global__ __launch_bounds__(256) void k_sup_t(
    const float* __restrict__ X,
    const float* __restrict__ Wl,    // [3,128,128]
    const float* __restrict__ Bcl,   // [3,128]
    const float* __restrict__ Whl,   // [128,128]
    const float* __restrict__ Bhl,   // [128]
    bf16_t* __restrict__ supt,       // [24,128,1024]  ([z][o][n])
    float* __restrict__ tbuf)        // [8192,128]
{
    __shared__ float As[64*68];
    __shared__ float Bs[64*68];
    const int t  = threadIdx.x;
    const int tx = t & 15, ty = t >> 4;
    const int r0 = blockIdx.x * 64;
    const int c0 = blockIdx.y * 64;

    float acc[4][4] = {};
    for (int k0 = 0; k0 < 128; k0 += 64) {
        const int low6 = t & 63;
        const int hi   = t >> 6;
        #pragma unroll
        for (int i = 0; i < 16; ++i) {
            int rl = hi + i*4;
            As[low6*68 + rl] = X[(r0+rl)*128 + k0 + low6];
        }
        #pragma unroll
        for (int i = 0; i < 16; ++i) {
            int kl = hi + i*4;
            int cg = c0 + low6;
            float v;
            if (cg < 384) {
                int d = cg >> 7, o = cg & 127;
                v = Wl[(d*128 + k0 + kl)*128 + o];
            } else {
                int o = cg - 384;
                v = Whl[(k0 + kl)*128 + o];
            }
            Bs[kl*68 + low6] = v;
        }
        __syncthreads();
        #pragma unroll
        for (int kk = 0; kk < 64; ++kk) {
            float4 a4 = *reinterpret_cast<const float4*>(&As[kk*68 + ty*4]);
            float4 b4 = *reinterpret_cast<const float4*>(&Bs[kk*68 + tx*4]);
            float av[4] = {a4.x, a4.y, a4.z, a4.w};
            float bv[4] = {b4.x, b4.y, b4.z, b4.w};
            #pragma unroll
            for (int i = 0; i < 4; ++i)
                #pragma unroll
                for (int j = 0; j < 4; ++j)
                    acc[i][j] += av[i] * bv[j];
        }
        __syncthreads();
    }
    #pragma unroll
    for (int i = 0; i < 4; ++i) {
        int r = r0 + ty*4 + i;
        int n = r >> 3, b = r & 7;
        #pragma unroll
        for (int j = 0; j < 4; ++j) {
            int cg = c0 + tx*4 + j;
            float v = acc[i][j];
            if (cg < 384) {
                int d = cg >> 7, o = cg & 127;
                supt[((size_t)(d*8 + b)*128 + o)*1024 + n] = (bf16_t)(v + Bcl[d*128 + o]);
            } else {
                int o = cg - 384;
                tbuf[(size_t)r*128 + o] = fmaxf(v + Bhl[o], 0.0f);
            }
        }
    }
}

// ---------------------------------------------------------------------------
// MFMA agg GEMM: aggb[z][m][o] = sum_n adjb[z][m][n] * supt[z][o][n]
// 128x128 tile, BK=64, 4 waves each 64x64 via 4x4 of 16x16x32 bf16 MFMA.
// grid (8, 24)
// ---------------------------------------------------------------------------
__global__ __launch_bounds__(256) void k_agg_mfma(
    const bf16_t* __restrict__ adjb,   // [24][1024][1024]
    const bf16_t* __restrict__ supt,   // [24][128][1024]
    bf16_t* __restrict__ aggb)         // [24][1024][128]
{
    __shared__ bf16_t As[128*64];      // [m][k]
    __shared__ bf16_t Bs[128*64];      // [o][k]  (B^T)
    const int t = threadIdx.x;
    const int lane = t & 63, w = t >> 6;
    const int wm = w & 1, wn = w >> 1;
    const int m0 = blockIdx.x * 128;
    const int z  = blockIdx.y;
    const bf16_t* Az = adjb + (size_t)z * 1024 * 1024;
    const bf16_t* Bz = supt + (size_t)z * 128 * 1024;

    f32x4 acc[4][4] = {};
    for (int k0 = 0; k0 < 1024; k0 += 64) {
        #pragma unroll
        for (int q = 0; q < 4; ++q) {
            int L = (w*4 + q)*64 + lane;          // 0..1023
            int row = L >> 3, seg = L & 7;
            GLOAD_LDS16(Az + (size_t)(m0 + row)*1024 + k0 + seg*8,
                        (char*)As + (w*4 + q)*1024);
        }
        #pragma unroll
        for (int q = 0; q < 4; ++q) {
            int L = (w*4 + q)*64 + lane;
            int row = L >> 3, seg = L & 7;
            GLOAD_LDS16(Bz + (size_t)row*1024 + k0 + seg*8,
                        (char*)Bs + (w*4 + q)*1024);
        }
        __syncthreads();
        #pragma unroll
        for (int ks = 0; ks < 64; ks += 32) {
            bf16x8 af[4], bfr[4];
            #pragma unroll
            for (int i = 0; i < 4; ++i) {
                int m = wm*64 + i*16 + (lane & 15);
                af[i] = *reinterpret_cast<const bf16x8*>(&As[m*64 + ks + ((lane >> 4) * 8)]);
                int o = wn*64 + i*16 + (lane & 15);
                bfr[i] = *reinterpret_cast<const bf16x8*>(&Bs[o*64 + ks + ((lane >> 4) * 8)]);
            }
            #pragma unroll
            for (int i = 0; i < 4; ++i)
                #pragma unroll
                for (int j = 0; j < 4; ++j)
                    acc[i][j] = __builtin_amdgcn_mfma_f32_16x16x32_bf16(af[i], bfr[j], acc[i][j], 0, 0, 0);
        }
        __syncthreads();
    }
    bf16_t* Cz = aggb + (size_t)z * 1024 * 128;
    #pragma unroll
    for (int i = 0; i < 4; ++i) {
        #pragma unroll
        for (int j = 0; j < 4; ++j) {
            int o = wn*64 + j*16 + (lane & 15);
            #pragma unroll
            for (int rg = 0; rg < 4; ++rg) {
                int m = m0 + wm*64 + i*16 + (lane >> 4)*4 + rg;
                Cz[(size_t)m*128 + o] = (bf16_t)acc[i][j][rg];
            }
        }
    }
}

// ---------------------------------------------------------------------------
// MFMA gi GEMM: gib[r][c] = bf16( sum_k aggb_flat[r][k] * Wihb[c][k] + bih[c] )
// r in [0,24576), c in [0,384). grid (192, 3). Same tile structure.
// ---------------------------------------------------------------------------
__global__ __launch_bounds__(256) void k_gi_mfma(
    const bf16_t* __restrict__ A,      // [24576][128]
    const bf16_t* __restrict__ Wb,     // [384][128]
    const float*  __restrict__ bias,   // [384]
    bf16_t* __restrict__ C)            // [24576][384]
{
    __shared__ bf16_t As[128*64];
    __shared__ bf16_t Bs[128*64];
    const int t = threadIdx.x;
    const int lane = t & 63, w = t >> 6;
    const int wm = w & 1, wn = w >> 1;
    const int m0 = blockIdx.x * 128;
    const int c0 = blockIdx.y * 128;

    f32x4 acc[4][4] = {};
    for (int k0 = 0; k0 < 128; k0 += 64) {
        #pragma unroll
        for (int q = 0; q < 4; ++q) {
            int L = (w*4 + q)*64 + lane;
            int row = L >> 3, seg = L & 7;
            GLOAD_LDS16(A + (size_t)(m0 + row)*128 + k0 + seg*8,
                        (char*)As + (w*4 + q)*1024);
        }
        #pragma unroll
        for (int q = 0; q < 4; ++q) {
            int L = (w*4 + q)*64 + lane;
            int row = L >> 3, seg = L & 7;
            GLOAD_LDS16(Wb + (size_t)(c0 + row)*128 + k0 + seg*8,
                        (char*)Bs + (w*4 + q)*1024);
        }
        __syncthreads();
        #pragma unroll
        for (int ks = 0; ks < 64; ks += 32) {
            bf16x8 af[4], bfr[4];
            #pragma unroll
            for (int i = 0; i < 4; ++i) {
                int m = wm*64 + i*16 + (lane & 15);
                af[i] = *reinterpret_cast<const bf16x8*>(&As[m*64 + ks + ((lane >> 4) * 8)]);
                int o = wn*64 + i*16 + (lane & 15);
                bfr[i] = *reinterpret_cast<const bf16x8*>(&Bs[o*64 + ks + ((lane >> 4) * 8)]);
            }
            #pragma unroll
            for (int i = 0; i < 4; ++i)
                #pragma unroll
                for (int j = 0; j < 4; ++j)
                    acc[i][j] = __builtin_amdgcn_mfma_f32_16x16x32_bf16(af[i], bfr[j], acc[i][j], 0, 0, 0);
        }
        __syncthreads();
    }
    #pragma unroll
    for (int i = 0; i < 4; ++i) {
        #pragma unroll
        for (int j = 0; j < 4; ++j) {
            int c = c0 + wn*64 + j*16 + (lane & 15);
            float bv = bias[c];
            #pragma unroll
            for (int rg = 0; rg < 4; ++rg) {
                int m = m0 + wm*64 + i*16 + (lane >> 4)*4 + rg;
                C[(size_t)m*G3 + c] = (bf16_t)(acc[i][j][rg] + bv);
            }
        }
    }
}

// ---------------------------------------------------------------------------
// GRU gates + sum over d + relu + highway blend.
// gi (bf16): [3,8,1024,384] rows ((d*8+b)*1024+n); gh (bf16): [8192,384] rows n*8+b
// ---------------------------------------------------------------------------
__global__ __launch_bounds__(256) void k_gates(
    const bf16_t* __restrict__ gi, const bf16_t* __restrict__ gh,
    const float* __restrict__ X, const float* __restrict__ tbuf,
    float* __restrict__ Xout)
{
    int idx = blockIdx.x * 256 + threadIdx.x;
    int r = idx >> 7, o = idx & 127;
    int n = r >> 3, b = r & 7;
    float h = X[idx];
    const bf16_t* ghr = gh + (size_t)r * G3;
    float g_r = (float)ghr[o], g_z = (float)ghr[128 + o], g_n = (float)ghr[256 + o];
    float acc = 0.0f;
    #pragma unroll
    for (int d = 0; d < 3; ++d) {
        const bf16_t* gir = gi + (size_t)((d*8 + b)*1024 + n) * G3;
        float i_r = (float)gir[o], i_z = (float)gir[128 + o], i_n = (float)gir[256 + o];
        float rg = 1.0f / (1.0f + expf(-(i_r + g_r)));
        float zg = 1.0f / (1.0f + expf(-(i_z + g_z)));
        float ng = tanhf(i_n + rg * g_n);
        acc += (1.0f - zg) * ng + zg * h;
    }
    float outv = fmaxf(acc, 0.0f);
    float tg = tbuf[idx];
    Xout[idx] = outv * tg + h * (1.0f - tg);
}

// ---------------------------------------------------------------------------
extern "C" void kernel_launch(void* const* d_in, const int* in_sizes, int n_in,
                              void* d_out, int out_size, void* d_ws, size_t ws_size,
                              hipStream_t stream) {
    const float* inputs = (const float*)d_in[0];   // [1024,8,128]
    const float* adj    = (const float*)d_in[1];   // [3,8,1024,1024]
    const float* W      = (const float*)d_in[2];   // [2,3,128,128]
    const float* Bc     = (const float*)d_in[3];   // [2,3,128]
    const float* Wh     = (const float*)d_in[4];   // [2,128,128]
    const float* Bh     = (const float*)d_in[5];   // [2,128]
    const float* Wih    = (const float*)d_in[6];   // [2,384,128]
    const float* Whh    = (const float*)d_in[7];   // [2,384,128]
    const float* bih    = (const float*)d_in[8];   // [2,384]
    const float* bhh    = (const float*)d_in[9];   // [2,384]

    char* ws = (char*)d_ws;
    float*  x1   = (float*)ws;                      ws += (size_t)NB*128*4;        // 4 MB
    float*  tbuf = (float*)ws;                      ws += (size_t)NB*128*4;        // 4 MB
    bf16_t* gh   = (bf16_t*)ws;                     ws += (size_t)NB*G3*2;         // 6 MB
    bf16_t* supt = (bf16_t*)ws;                     ws += (size_t)24*128*1024*2;   // 6 MB
    bf16_t* aggb = (bf16_t*)ws;                     ws += (size_t)24*1024*128*2;   // 6 MB
    bf16_t* gib  = (bf16_t*)ws;                     ws += (size_t)3*NB*G3*2;       // 18 MB
    bf16_t* wihb = (bf16_t*)ws;                     ws += (size_t)2*G3*128*2;      // 0.2 MB
    bf16_t* adjb = (bf16_t*)ws;                                                    // 50.3 MB

    // one-time conversions (adj reused by both layers)
    k_cvt<<<dim3(4096), dim3(256), 0, stream>>>(adj, adjb, 3*8*1024*1024/4);
    k_cvt<<<dim3(96),   dim3(256), 0, stream>>>(Wih, wihb, 2*G3*128/4);

    for (int l = 0; l < 2; ++l) {
        const float* xin = (l == 0) ? inputs : x1;
        float* xout = (l == 1) ? (float*)d_out : x1;

        // support (3 dirs, bf16 transposed) + highway t (fp32)
        k_sup_t<<<dim3(128, 8), dim3(256), 0, stream>>>(
            xin, W + l*3*128*128, Bc + l*3*128, Wh + l*128*128, Bh + l*128,
            supt, tbuf);
        // gh = x @ Whh^T + bhh (d-independent), bf16 out
        gemm_abt<<<dim3(128, 6), dim3(256), 0, stream>>>(
            xin, Whh + l*G3*128, bhh + l*G3, gh, NB);
        // agg = adj @ support (24 batched MFMA GEMMs)
        k_agg_mfma<<<dim3(8, 24), dim3(256), 0, stream>>>(adjb, supt, aggb);
        // gi = agg @ Wih^T + bih (MFMA)
        k_gi_mfma<<<dim3(192, 3), dim3(256), 0, stream>>>(
            aggb, wihb + l*G3*128, bih + l*G3, gib);
        // gates + sum_d + relu + highway
        k_gates<<<dim3(4096), dim3(256), 0, stream>>>(gib, gh, xin, tbuf, xout);
    }
}

// Round 4
// 384.591 us; speedup vs baseline: 1.4508x; 1.0265x over previous
//
#include <hip/hip_runtime.h>
#include <math.h>

// Problem constants (fixed by the reference)
#define N_NODES 1024
#define BATCH   8
#define FEAT    128        // F == O
#define NDIR    3
#define NB      (N_NODES*BATCH)   // 8192
#define G3      384               // 3*O

typedef __bf16 bf16_t;
using bf16x8 = __attribute__((ext_vector_type(8))) __bf16;
using bf16x4 = __attribute__((ext_vector_type(4))) __bf16;
using f32x4  = __attribute__((ext_vector_type(4))) float;

// async global->LDS 16B per lane; LDS dest must be wave-uniform base (+lane*16)
#define GLOAD_LDS16(g, l) \
    __builtin_amdgcn_global_load_lds((const __attribute__((address_space(1))) void*)(g), \
                                     (__attribute__((address_space(3))) void*)(l), 16, 0, 0)

// ---------------------------------------------------------------------------
// adj fp32 -> CENTERED bf16 (adj - 0.5): halves quantization abs error.
// agg is reconstructed as (adjc @ sup) + 0.5*colsum(sup).
// ---------------------------------------------------------------------------
__global__ __launch_bounds__(256) void k_cvt_adj(
    const float* __restrict__ src, bf16_t* __restrict__ dst, int n4)
{
    int i = blockIdx.x * 256 + threadIdx.x;
    int stride = gridDim.x * 256;
    for (; i < n4; i += stride) {
        float4 v = reinterpret_cast<const float4*>(src)[i];
        bf16x4 o;
        o[0] = (bf16_t)(v.x - 0.5f); o[1] = (bf16_t)(v.y - 0.5f);
        o[2] = (bf16_t)(v.z - 0.5f); o[3] = (bf16_t)(v.w - 0.5f);
        *reinterpret_cast<bf16x4*>(&dst[(size_t)i * 4]) = o;
    }
}

// ---------------------------------------------------------------------------
// Weight prep, hi/lo split concats (K'=384):
//  m in [0,384)   : W[l][d][k][o]  -> wsup rows, pattern A [hi|lo|hi]
//  m in [384,512) : Wh[l][k][o]    -> wsup rows, pattern A
//  m in [512,896) : Whh[l][c][k]   -> whhc rows, pattern A   (vs xcat [xhi|xhi|xlo])
//  m in [896,1280): Wih[l][c][k]   -> wihc rows, pattern B [hi|hi|lo] (vs aggcat [hi|lo|hi])
// grid (1280, 2), 128 threads (tid = k)
// ---------------------------------------------------------------------------
__global__ __launch_bounds__(128) void k_wprep(
    const float* __restrict__ W, const float* __restrict__ Wh,
    const float* __restrict__ Whh, const float* __restrict__ Wih,
    bf16_t* __restrict__ wsup,    // [2][512][384]
    bf16_t* __restrict__ whhc,    // [2][384][384]
    bf16_t* __restrict__ wihc)    // [2][384][384]
{
    int m = blockIdx.x, l = blockIdx.y, k = threadIdx.x;
    float w;
    bf16_t* dst;
    bool patB = false;
    if (m < 384) {
        int d = m >> 7, o = m & 127;
        w = W[((size_t)(l*3 + d)*128 + k)*128 + o];
        dst = wsup + ((size_t)l*512 + m)*384;
    } else if (m < 512) {
        int o = m - 384;
        w = Wh[((size_t)l*128 + k)*128 + o];
        dst = wsup + ((size_t)l*512 + m)*384;
    } else if (m < 896) {
        int c = m - 512;
        w = Whh[((size_t)l*384 + c)*128 + k];
        dst = whhc + ((size_t)l*384 + c)*384;
    } else {
        int c = m - 896;
        w = Wih[((size_t)l*384 + c)*128 + k];
        dst = wihc + ((size_t)l*384 + c)*384;
        patB = true;
    }
    bf16_t hi = (bf16_t)w;
    bf16_t lo = (bf16_t)(w - (float)hi);
    if (patB) { dst[k] = hi; dst[128 + k] = hi; dst[256 + k] = lo; }
    else      { dst[k] = hi; dst[128 + k] = lo; dst[256 + k] = hi; }
}

// ---------------------------------------------------------------------------
// x-cat build (layer 0): inputs fp32 [N,B,128] -> xcat [8][1024][384] = [hi|hi|lo]
// ---------------------------------------------------------------------------
__global__ __launch_bounds__(256) void k_xcat(
    const float* __restrict__ X, bf16_t* __restrict__ xcat)
{
    int idx = blockIdx.x * 256 + threadIdx.x;   // over 8192*128
    int k = idx & 127, r = idx >> 7;
    int n = r >> 3, b = r & 7;
    float v = X[idx];
    bf16_t hi = (bf16_t)v;
    bf16_t lo = (bf16_t)(v - (float)hi);
    bf16_t* dst = xcat + ((size_t)(b*1024 + n))*384 + k;
    dst[0] = hi; dst[128] = hi; dst[256] = lo;
}

// ---------------------------------------------------------------------------
// MFMA support+highway kernel (hi/lo exact):
//   C[m][n] = sum_k' wsup[m][k'] * xcat[b*1024+n][k']   (K'=384)
//   m<384 : supt[((m>>7)*8+b)*128 + (m&127)][n] = bf16(C + Bc)
//   m>=384: tbuf[(b*128 + m-384)*1024 + n]     = relu(C + Bh)  (fp32)
// grid (8, 4, 8), 256 threads.
// ---------------------------------------------------------------------------
__global__ __launch_bounds__(256) void k_sup(
    const bf16_t* __restrict__ Wcat,  // [512][384] (this layer)
    const bf16_t* __restrict__ xcat,  // [8][1024][384]
    const float* __restrict__ Bcl,    // [3,128]
    const float* __restrict__ Bhl,    // [128]
    bf16_t* __restrict__ supt,        // [24][128][1024]
    float* __restrict__ tbuf)         // [8][128][1024]
{
    __shared__ bf16_t As[128*64];
    __shared__ bf16_t Bs[128*64];
    const int t = threadIdx.x;
    const int lane = t & 63, w = t >> 6;
    const int wm = w & 1, wn = w >> 1;
    const int n0 = blockIdx.x * 128;
    const int m0 = blockIdx.y * 128;
    const int b  = blockIdx.z;
    const bf16_t* Xb = xcat + (size_t)b * 1024 * 384;

    f32x4 acc[4][4] = {};
    for (int k0 = 0; k0 < 384; k0 += 64) {
        #pragma unroll
        for (int q = 0; q < 4; ++q) {
            int L = (w*4 + q)*64 + lane;
            int row = L >> 3, seg = L & 7;
            GLOAD_LDS16(Wcat + (size_t)(m0 + row)*384 + k0 + seg*8,
                        (char*)As + (w*4 + q)*1024);
        }
        #pragma unroll
        for (int q = 0; q < 4; ++q) {
            int L = (w*4 + q)*64 + lane;
            int row = L >> 3, seg = L & 7;
            GLOAD_LDS16(Xb + (size_t)(n0 + row)*384 + k0 + seg*8,
                        (char*)Bs + (w*4 + q)*1024);
        }
        __syncthreads();
        #pragma unroll
        for (int ks = 0; ks < 64; ks += 32) {
            bf16x8 af[4], bfr[4];
            #pragma unroll
            for (int i = 0; i < 4; ++i) {
                int m = wm*64 + i*16 + (lane & 15);
                af[i] = *reinterpret_cast<const bf16x8*>(&As[m*64 + ks + ((lane >> 4) * 8)]);
                int n = wn*64 + i*16 + (lane & 15);
                bfr[i] = *reinterpret_cast<const bf16x8*>(&Bs[n*64 + ks + ((lane >> 4) * 8)]);
            }
            #pragma unroll
            for (int i = 0; i < 4; ++i)
                #pragma unroll
                for (int j = 0; j < 4; ++j)
                    acc[i][j] = __builtin_amdgcn_mfma_f32_16x16x32_bf16(af[i], bfr[j], acc[i][j], 0, 0, 0);
        }
        __syncthreads();
    }
    #pragma unroll
    for (int i = 0; i < 4; ++i) {
        #pragma unroll
        for (int j = 0; j < 4; ++j) {
            int n = n0 + wn*64 + j*16 + (lane & 15);
            #pragma unroll
            for (int rg = 0; rg < 4; ++rg) {
                int m = m0 + wm*64 + i*16 + (lane >> 4)*4 + rg;
                float v = acc[i][j][rg];
                if (m < 384) {
                    int d = m >> 7, o = m & 127;
                    supt[((size_t)((d*8 + b)*128 + o))*1024 + n] = (bf16_t)(v + Bcl[d*128 + o]);
                } else {
                    int o = m - 384;
                    tbuf[((size_t)(b*128 + o))*1024 + n] = fmaxf(v + Bhl[o], 0.0f);
                }
            }
        }
    }
}

// ---------------------------------------------------------------------------
// colsum[row] = sum_n supt[row][n]  (row = z*128+o, 3072 rows), fp32.
// grid 768, 256 threads: 4 waves, one row per wave.
// ---------------------------------------------------------------------------
__global__ __launch_bounds__(256) void k_colsum(
    const bf16_t* __restrict__ supt, float* __restrict__ colsum)
{
    int row = blockIdx.x * 4 + (threadIdx.x >> 6);
    int lane = threadIdx.x & 63;
    const bf16_t* p = supt + (size_t)row * 1024 + lane * 16;
    bf16x8 v0 = *reinterpret_cast<const bf16x8*>(p);
    bf16x8 v1 = *reinterpret_cast<const bf16x8*>(p + 8);
    float s = 0.0f;
    #pragma unroll
    for (int i = 0; i < 8; ++i) s += (float)v0[i] + (float)v1[i];
    #pragma unroll
    for (int off = 32; off > 0; off >>= 1) s += __shfl_down(s, off, 64);
    if (lane == 0) colsum[row] = s;
}

// ---------------------------------------------------------------------------
// Generic MFMA GEMM (bf16 out): C[m][c] = bf16(sum_k A[m][k]*B[c][k] + bias[c])
// used for gh only now (A=xcat K=384, B=whhc). grid (M/128, 3).
// ---------------------------------------------------------------------------
__global__ __launch_bounds__(256) void k_gemm_bt(
    const bf16_t* __restrict__ A, const bf16_t* __restrict__ B,
    const float* __restrict__ bias, bf16_t* __restrict__ C, int K)
{
    __shared__ bf16_t As[128*64];
    __shared__ bf16_t Bs[128*64];
    const int t = threadIdx.x;
    const int lane = t & 63, w = t >> 6;
    const int wm = w & 1, wn = w >> 1;
    const int m0 = blockIdx.x * 128;
    const int c0 = blockIdx.y * 128;

    f32x4 acc[4][4] = {};
    for (int k0 = 0; k0 < K; k0 += 64) {
        #pragma unroll
        for (int q = 0; q < 4; ++q) {
            int L = (w*4 + q)*64 + lane;
            int row = L >> 3, seg = L & 7;
            GLOAD_LDS16(A + (size_t)(m0 + row)*K + k0 + seg*8,
                        (char*)As + (w*4 + q)*1024);
        }
        #pragma unroll
        for (int q = 0; q < 4; ++q) {
            int L = (w*4 + q)*64 + lane;
            int row = L >> 3, seg = L & 7;
            GLOAD_LDS16(B + (size_t)(c0 + row)*K + k0 + seg*8,
                        (char*)Bs + (w*4 + q)*1024);
        }
        __syncthreads();
        #pragma unroll
        for (int ks = 0; ks < 64; ks += 32) {
            bf16x8 af[4], bfr[4];
            #pragma unroll
            for (int i = 0; i < 4; ++i) {
                int m = wm*64 + i*16 + (lane & 15);
                af[i] = *reinterpret_cast<const bf16x8*>(&As[m*64 + ks + ((lane >> 4) * 8)]);
                int c = wn*64 + i*16 + (lane & 15);
                bfr[i] = *reinterpret_cast<const bf16x8*>(&Bs[c*64 + ks + ((lane >> 4) * 8)]);
            }
            #pragma unroll
            for (int i = 0; i < 4; ++i)
                #pragma unroll
                for (int j = 0; j < 4; ++j)
                    acc[i][j] = __builtin_amdgcn_mfma_f32_16x16x32_bf16(af[i], bfr[j], acc[i][j], 0, 0, 0);
        }
        __syncthreads();
    }
    #pragma unroll
    for (int i = 0; i < 4; ++i) {
        #pragma unroll
        for (int j = 0; j < 4; ++j) {
            int c = c0 + wn*64 + j*16 + (lane & 15);
            float bv = bias[c];
            #pragma unroll
            for (int rg = 0; rg < 4; ++rg) {
                int m = m0 + wm*64 + i*16 + (lane >> 4)*4 + rg;
                C[(size_t)m*G3 + c] = (bf16_t)(acc[i][j][rg] + bv);
            }
        }
    }
}

// ---------------------------------------------------------------------------
// MFMA agg GEMM: agg[z][m][o] = sum_n adjc[z][m][n]*supt[z][o][n] + 0.5*colsum[z][o]
// Output: aggcat [24576][384] = [hi|lo|hi] (exact hi/lo split of fp32 agg).
// grid (8, 24)
// ---------------------------------------------------------------------------
__global__ __launch_bounds__(256) void k_agg_mfma(
    const bf16_t* __restrict__ adjb,   // [24][1024][1024] centered
    const bf16_t* __restrict__ supt,   // [24][128][1024]
    const float* __restrict__ colsum,  // [24][128]
    bf16_t* __restrict__ aggcat)       // [24576][384]
{
    __shared__ bf16_t As[128*64];
    __shared__ bf16_t Bs[128*64];
    const int t = threadIdx.x;
    const int lane = t & 63, w = t >> 6;
    const int wm = w & 1, wn = w >> 1;
    const int m0 = blockIdx.x * 128;
    const int z  = blockIdx.y;
    const bf16_t* Az = adjb + (size_t)z * 1024 * 1024;
    const bf16_t* Bz = supt + (size_t)z * 128 * 1024;

    f32x4 acc[4][4] = {};
    for (int k0 = 0; k0 < 1024; k0 += 64) {
        #pragma unroll
        for (int q = 0; q < 4; ++q) {
            int L = (w*4 + q)*64 + lane;
            int row = L >> 3, seg = L & 7;
            GLOAD_LDS16(Az + (size_t)(m0 + row)*1024 + k0 + seg*8,
                        (char*)As + (w*4 + q)*1024);
        }
        #pragma unroll
        for (int q = 0; q < 4; ++q) {
            int L = (w*4 + q)*64 + lane;
            int row = L >> 3, seg = L & 7;
            GLOAD_LDS16(Bz + (size_t)row*1024 + k0 + seg*8,
                        (char*)Bs + (w*4 + q)*1024);
        }
        __syncthreads();
        #pragma unroll
        for (int ks = 0; ks < 64; ks += 32) {
            bf16x8 af[4], bfr[4];
            #pragma unroll
            for (int i = 0; i < 4; ++i) {
                int m = wm*64 + i*16 + (lane & 15);
                af[i] = *reinterpret_cast<const bf16x8*>(&As[m*64 + ks + ((lane >> 4) * 8)]);
                int o = wn*64 + i*16 + (lane & 15);
                bfr[i] = *reinterpret_cast<const bf16x8*>(&Bs[o*64 + ks + ((lane >> 4) * 8)]);
            }
            #pragma unroll
            for (int i = 0; i < 4; ++i)
                #pragma unroll
                for (int j = 0; j < 4; ++j)
                    acc[i][j] = __builtin_amdgcn_mfma_f32_16x16x32_bf16(af[i], bfr[j], acc[i][j], 0, 0, 0);
        }
        __syncthreads();
    }
    float cs[4];
    #pragma unroll
    for (int j = 0; j < 4; ++j)
        cs[j] = 0.5f * colsum[z*128 + wn*64 + j*16 + (lane & 15)];
    #pragma unroll
    for (int i = 0; i < 4; ++i) {
        #pragma unroll
        for (int j = 0; j < 4; ++j) {
            int o = wn*64 + j*16 + (lane & 15);
            #pragma unroll
            for (int rg = 0; rg < 4; ++rg) {
                size_t m = (size_t)z*1024 + m0 + wm*64 + i*16 + (lane >> 4)*4 + rg;
                float v = acc[i][j][rg] + cs[j];
                bf16_t hi = (bf16_t)v;
                bf16_t lo = (bf16_t)(v - (float)hi);
                bf16_t* row = aggcat + m*384;
                row[o] = hi; row[128 + o] = lo; row[256 + o] = hi;
            }
        }
    }
}

// ---------------------------------------------------------------------------
// MFMA gi GEMM: gi[m][c] = sum_k' aggcat[m][k']*wihc[c][k'] + bih[c]  (K'=384)
// c<256 (i_r,i_z): bf16 -> girz[m][c];  c>=256 (i_n): fp32 -> gin[m][c-256]
// grid (192, 3) — blockIdx.y==2 is the fp32 region (uniform per block).
// ---------------------------------------------------------------------------
__global__ __launch_bounds__(256) void k_gi(
    const bf16_t* __restrict__ A,      // [24576][384]
    const bf16_t* __restrict__ B,      // [384][384]
    const float*  __restrict__ bias,   // [384]
    bf16_t* __restrict__ girz,         // [24576][256]
    float* __restrict__ gin)           // [24576][128]
{
    __shared__ bf16_t As[128*64];
    __shared__ bf16_t Bs[128*64];
    const int t = threadIdx.x;
    const int lane = t & 63, w = t >> 6;
    const int wm = w & 1, wn = w >> 1;
    const int m0 = blockIdx.x * 128;
    const int c0 = blockIdx.y * 128;

    f32x4 acc[4][4] = {};
    for (int k0 = 0; k0 < 384; k0 += 64) {
        #pragma unroll
        for (int q = 0; q < 4; ++q) {
            int L = (w*4 + q)*64 + lane;
            int row = L >> 3, seg = L & 7;
            GLOAD_LDS16(A + (size_t)(m0 + row)*384 + k0 + seg*8,
                        (char*)As + (w*4 + q)*1024);
        }
        #pragma unroll
        for (int q = 0; q < 4; ++q) {
            int L = (w*4 + q)*64 + lane;
            int row = L >> 3, seg = L & 7;
            GLOAD_LDS16(B + (size_t)(c0 + row)*384 + k0 + seg*8,
                        (char*)Bs + (w*4 + q)*1024);
        }
        __syncthreads();
        #pragma unroll
        for (int ks = 0; ks < 64; ks += 32) {
            bf16x8 af[4], bfr[4];
            #pragma unroll
            for (int i = 0; i < 4; ++i) {
                int m = wm*64 + i*16 + (lane & 15);
                af[i] = *reinterpret_cast<const bf16x8*>(&As[m*64 + ks + ((lane >> 4) * 8)]);
                int c = wn*64 + i*16 + (lane & 15);
                bfr[i] = *reinterpret_cast<const bf16x8*>(&Bs[c*64 + ks + ((lane >> 4) * 8)]);
            }
            #pragma unroll
            for (int i = 0; i < 4; ++i)
                #pragma unroll
                for (int j = 0; j < 4; ++j)
                    acc[i][j] = __builtin_amdgcn_mfma_f32_16x16x32_bf16(af[i], bfr[j], acc[i][j], 0, 0, 0);
        }
        __syncthreads();
    }
    #pragma unroll
    for (int i = 0; i < 4; ++i) {
        #pragma unroll
        for (int j = 0; j < 4; ++j) {
            int c = c0 + wn*64 + j*16 + (lane & 15);
            float bv = bias[c];
            #pragma unroll
            for (int rg = 0; rg < 4; ++rg) {
                int m = m0 + wm*64 + i*16 + (lane >> 4)*4 + rg;
                float v = acc[i][j][rg] + bv;
                if (c < 256) girz[(size_t)m*256 + c] = (bf16_t)v;
                else         gin[(size_t)m*128 + (c - 256)] = v;
            }
        }
    }
}

// ---------------------------------------------------------------------------
// GRU gates + sum over d + relu + highway blend.
// h reconstructed exactly from xcat (hi+lo). Optionally writes d_out (fp32,
// [n][b][o] layout) and/or updates xcat in place for the next layer
// (each element's reader is its own writer -> in-place safe).
// grid (64 n-blocks of 16, 8 b), 256 threads.
// ---------------------------------------------------------------------------
__global__ __launch_bounds__(256) void k_gates(
    const bf16_t* __restrict__ girz, const float* __restrict__ gin,
    const bf16_t* __restrict__ ghb,
    bf16_t* xcat,                       // NOT restrict: read+write same buffer
    const float* __restrict__ tbuf,
    float* __restrict__ Xout, int write_xcat)
{
    __shared__ float ts[128*17];
    const int b = blockIdx.y, n0 = blockIdx.x * 16;
    const int tid = threadIdx.x;
    {
        int o = tid >> 1, nh = (tid & 1) * 8;
        const float* src = tbuf + ((size_t)(b*128 + o))*1024 + n0 + nh;
        float4 v0 = *reinterpret_cast<const float4*>(src);
        float4 v1 = *reinterpret_cast<const float4*>(src + 4);
        float* dst = &ts[o*17 + nh];
        dst[0]=v0.x; dst[1]=v0.y; dst[2]=v0.z; dst[3]=v0.w;
        dst[4]=v1.x; dst[5]=v1.y; dst[6]=v1.z; dst[7]=v1.w;
    }
    __syncthreads();
    #pragma unroll
    for (int p = 0; p < 8; ++p) {
        int e = p*256 + tid;
        int nn = e >> 7, o = e & 127;
        int n = n0 + nn;
        size_t rb = (size_t)(b*1024 + n);
        bf16_t* xr = xcat + rb*384;
        float h = (float)xr[o] + (float)xr[256 + o];
        const bf16_t* ghr = ghb + rb*G3;
        float g_r = (float)ghr[o], g_z = (float)ghr[128+o], g_n = (float)ghr[256+o];
        float acc = 0.0f;
        #pragma unroll
        for (int d = 0; d < 3; ++d) {
            size_t rr = (size_t)((d*8 + b)*1024 + n);
            float i_r = (float)girz[rr*256 + o];
            float i_z = (float)girz[rr*256 + 128 + o];
            float i_n = gin[rr*128 + o];
            float rg = 1.0f / (1.0f + expf(-(i_r + g_r)));
            float zg = 1.0f / (1.0f + expf(-(i_z + g_z)));
            float ng = tanhf(i_n + rg * g_n);
            acc += (1.0f - zg) * ng + zg * h;
        }
        float outv = fmaxf(acc, 0.0f);
        float tg = ts[o*17 + nn];
        float res = outv * tg + h * (1.0f - tg);
        if (Xout) Xout[(size_t)(n*8 + b)*128 + o] = res;
        if (write_xcat) {
            bf16_t hi = (bf16_t)res;
            bf16_t lo = (bf16_t)(res - (float)hi);
            xr[o] = hi; xr[128 + o] = hi; xr[256 + o] = lo;
        }
    }
}

// ---------------------------------------------------------------------------
extern "C" void kernel_launch(void* const* d_in, const int* in_sizes, int n_in,
                              void* d_out, int out_size, void* d_ws, size_t ws_size,
                              hipStream_t stream) {
    const float* inputs = (const float*)d_in[0];   // [1024,8,128]
    const float* adj    = (const float*)d_in[1];   // [3,8,1024,1024]
    const float* W      = (const float*)d_in[2];   // [2,3,128,128]
    const float* Bc     = (const float*)d_in[3];   // [2,3,128]
    const float* Wh     = (const float*)d_in[4];   // [2,128,128]
    const float* Bh     = (const float*)d_in[5];   // [2,128]
    const float* Wih    = (const float*)d_in[6];   // [2,384,128]
    const float* Whh    = (const float*)d_in[7];   // [2,384,128]
    const float* bih    = (const float*)d_in[8];   // [2,384]
    const float* bhh    = (const float*)d_in[9];   // [2,384]

    char* ws = (char*)d_ws;
    float*  tbuf   = (float*)ws;   ws += (size_t)8*128*1024*4;      // 4.19 MB
    bf16_t* xcat   = (bf16_t*)ws;  ws += (size_t)8*1024*384*2;      // 6.29 MB
    bf16_t* ghb    = (bf16_t*)ws;  ws += (size_t)NB*G3*2;           // 6.29 MB
    bf16_t* supt   = (bf16_t*)ws;  ws += (size_t)24*128*1024*2;     // 6.29 MB
    bf16_t* aggcat = (bf16_t*)ws;  ws += (size_t)3*NB*384*2;        // 18.87 MB
    bf16_t* girz   = (bf16_t*)ws;  ws += (size_t)3*NB*256*2;        // 12.58 MB
    float*  gin    = (float*)ws;   ws += (size_t)3*NB*128*4;        // 12.58 MB
    float*  colsum = (float*)ws;   ws += (size_t)24*128*4;          // 12 KB
    bf16_t* wsup   = (bf16_t*)ws;  ws += (size_t)2*512*384*2;       // 0.79 MB
    bf16_t* whhc   = (bf16_t*)ws;  ws += (size_t)2*384*384*2;       // 1.18 MB
    bf16_t* wihc   = (bf16_t*)ws;  ws += (size_t)2*384*384*2;       // 1.18 MB
    bf16_t* adjb   = (bf16_t*)ws;                                   // 50.33 MB  (~120.4 total)

    // one-time preps
    k_cvt_adj<<<dim3(4096), dim3(256), 0, stream>>>(adj, adjb, 3*8*1024*1024/4);
    k_wprep<<<dim3(1280, 2), dim3(128), 0, stream>>>(W, Wh, Whh, Wih, wsup, whhc, wihc);
    k_xcat<<<dim3(4096), dim3(256), 0, stream>>>(inputs, xcat);

    for (int l = 0; l < 2; ++l) {
        // support (bf16 [z][o][n]) + highway t (fp32 [b][o][n]) — hi/lo exact
        k_sup<<<dim3(8, 4, 8), dim3(256), 0, stream>>>(
            wsup + (size_t)l*512*384, xcat, Bc + l*3*128, Bh + l*128, supt, tbuf);
        // column sums of support (for centered-adj correction)
        k_colsum<<<dim3(768), dim3(256), 0, stream>>>(supt, colsum);
        // gh = x @ Whh^T + bhh — hi/lo exact
        k_gemm_bt<<<dim3(64, 3), dim3(256), 0, stream>>>(
            xcat, whhc + (size_t)l*384*384, bhh + l*G3, ghb, 384);
        // agg = adjc @ support + 0.5*colsum, output hi/lo-cat
        k_agg_mfma<<<dim3(8, 24), dim3(256), 0, stream>>>(adjb, supt, colsum, aggcat);
        // gi = agg @ Wih^T + bih (K'=384, agg & Wih exact via hi/lo)
        k_gi<<<dim3(192, 3), dim3(256), 0, stream>>>(
            aggcat, wihc + (size_t)l*384*384, bih + l*G3, girz, gin);
        // gates + sum_d + relu + highway; layer0 -> xcat update, layer1 -> d_out
        k_gates<<<dim3(64, 8), dim3(256), 0, stream>>>(
            girz, gin, ghb, xcat, tbuf,
            (l == 1) ? (float*)d_out : (float*)nullptr, (l == 0) ? 1 : 0);
    }
}

// Round 5
// 344.266 us; speedup vs baseline: 1.6208x; 1.1171x over previous
//
#include <hip/hip_runtime.h>
#include <math.h>

// Problem constants (fixed by the reference)
#define N_NODES 1024
#define BATCH   8
#define FEAT    128        // F == O
#define NDIR    3
#define NB      (N_NODES*BATCH)   // 8192
#define G3      384               // 3*O

typedef __bf16 bf16_t;
using bf16x8 = __attribute__((ext_vector_type(8))) __bf16;
using bf16x4 = __attribute__((ext_vector_type(4))) __bf16;
using f32x4  = __attribute__((ext_vector_type(4))) float;

// async global->LDS 16B per lane; LDS dest must be wave-uniform base (+lane*16)
#define GLOAD_LDS16(g, l) \
    __builtin_amdgcn_global_load_lds((const __attribute__((address_space(1))) void*)(g), \
                                     (__attribute__((address_space(3))) void*)(l), 16, 0, 0)

// ---------------------------------------------------------------------------
// 64x64-tile MFMA GEMM main-loop helpers (4 waves, 16-row strip per wave).
// As/Bs: [64 rows][64 k] bf16, k-contiguous. Stage one 64-k chunk:
//   call q in {2w, 2w+1}: rows q*8+(lane>>3), seg lane&7.
// ---------------------------------------------------------------------------
#define STAGE64(As, Bs, Arow, Brow, sA, sB, k0, w, lane)                      \
    {                                                                          \
        _Pragma("unroll")                                                      \
        for (int q = 0; q < 2; ++q) {                                          \
            int qq = (w)*2 + q;                                                \
            int row = qq*8 + ((lane) >> 3), seg = (lane) & 7;                  \
            GLOAD_LDS16((Arow) + (size_t)row*(sA) + (k0) + seg*8,              \
                        (char*)(As) + qq*1024);                                \
            GLOAD_LDS16((Brow) + (size_t)row*(sB) + (k0) + seg*8,              \
                        (char*)(Bs) + qq*1024);                                \
        }                                                                      \
    }

#define MFMA64(As, Bs, acc, w, lane)                                           \
    {                                                                          \
        _Pragma("unroll")                                                      \
        for (int ks = 0; ks < 64; ks += 32) {                                  \
            bf16x8 af = *reinterpret_cast<const bf16x8*>(                      \
                &(As)[((w)*16 + ((lane) & 15))*64 + ks + (((lane) >> 4) * 8)]);\
            _Pragma("unroll")                                                  \
            for (int j = 0; j < 4; ++j) {                                      \
                bf16x8 bfv = *reinterpret_cast<const bf16x8*>(                 \
                    &(Bs)[(j*16 + ((lane) & 15))*64 + ks + (((lane) >> 4) * 8)]);\
                (acc)[j] = __builtin_amdgcn_mfma_f32_16x16x32_bf16(af, bfv, (acc)[j], 0, 0, 0); \
            }                                                                  \
        }                                                                      \
    }

// ---------------------------------------------------------------------------
// adj fp32 -> CENTERED bf16 (adj - 0.5): halves quantization abs error.
// ---------------------------------------------------------------------------
__global__ __launch_bounds__(256) void k_cvt_adj(
    const float* __restrict__ src, bf16_t* __restrict__ dst, int n4)
{
    int i = blockIdx.x * 256 + threadIdx.x;
    int stride = gridDim.x * 256;
    for (; i < n4; i += stride) {
        float4 v = reinterpret_cast<const float4*>(src)[i];
        bf16x4 o;
        o[0] = (bf16_t)(v.x - 0.5f); o[1] = (bf16_t)(v.y - 0.5f);
        o[2] = (bf16_t)(v.z - 0.5f); o[3] = (bf16_t)(v.w - 0.5f);
        *reinterpret_cast<bf16x4*>(&dst[(size_t)i * 4]) = o;
    }
}

// ---------------------------------------------------------------------------
// Weight prep, hi/lo split concats (K'=384):
//  m<384: W -> wsup (pattern A [hi|lo|hi]); m in [384,512): Wh -> wsup (A)
//  m in [512,896): Whh -> whhc (A);  m in [896,1280): Wih -> wihc (B [hi|hi|lo])
// ---------------------------------------------------------------------------
__global__ __launch_bounds__(128) void k_wprep(
    const float* __restrict__ W, const float* __restrict__ Wh,
    const float* __restrict__ Whh, const float* __restrict__ Wih,
    bf16_t* __restrict__ wsup,    // [2][512][384]
    bf16_t* __restrict__ whhc,    // [2][384][384]
    bf16_t* __restrict__ wihc)    // [2][384][384]
{
    int m = blockIdx.x, l = blockIdx.y, k = threadIdx.x;
    float w;
    bf16_t* dst;
    bool patB = false;
    if (m < 384) {
        int d = m >> 7, o = m & 127;
        w = W[((size_t)(l*3 + d)*128 + k)*128 + o];
        dst = wsup + ((size_t)l*512 + m)*384;
    } else if (m < 512) {
        int o = m - 384;
        w = Wh[((size_t)l*128 + k)*128 + o];
        dst = wsup + ((size_t)l*512 + m)*384;
    } else if (m < 896) {
        int c = m - 512;
        w = Whh[((size_t)l*384 + c)*128 + k];
        dst = whhc + ((size_t)l*384 + c)*384;
    } else {
        int c = m - 896;
        w = Wih[((size_t)l*384 + c)*128 + k];
        dst = wihc + ((size_t)l*384 + c)*384;
        patB = true;
    }
    bf16_t hi = (bf16_t)w;
    bf16_t lo = (bf16_t)(w - (float)hi);
    if (patB) { dst[k] = hi; dst[128 + k] = hi; dst[256 + k] = lo; }
    else      { dst[k] = hi; dst[128 + k] = lo; dst[256 + k] = hi; }
}

// ---------------------------------------------------------------------------
// x-cat build (layer 0): inputs fp32 [N,B,128] -> xcat [8][1024][384] = [hi|hi|lo]
// ---------------------------------------------------------------------------
__global__ __launch_bounds__(256) void k_xcat(
    const float* __restrict__ X, bf16_t* __restrict__ xcat)
{
    int idx = blockIdx.x * 256 + threadIdx.x;   // over 8192*128
    int k = idx & 127, r = idx >> 7;
    int n = r >> 3, b = r & 7;
    float v = X[idx];
    bf16_t hi = (bf16_t)v;
    bf16_t lo = (bf16_t)(v - (float)hi);
    bf16_t* dst = xcat + ((size_t)(b*1024 + n))*384 + k;
    dst[0] = hi; dst[128] = hi; dst[256] = lo;
}

// ---------------------------------------------------------------------------
// k_sup (64x64): C[m][n] = sum_k' wsup[m][k'] * xcat[b][n][k']  (K'=384)
//  m<384 : supt[((m>>7)*8+b)*128 + (m&127)][n] = bf16(C + Bc)
//  m>=384: tbuf[(b*128 + m-384)][n] = relu(C + Bh)  (fp32)
// grid (16 n-tiles, 8 m-tiles, 8 b)
// ---------------------------------------------------------------------------
__global__ __launch_bounds__(256, 4) void k_sup(
    const bf16_t* __restrict__ Wcat,  // [512][384]
    const bf16_t* __restrict__ xcat,  // [8][1024][384]
    const float* __restrict__ Bcl,    // [3,128]
    const float* __restrict__ Bhl,    // [128]
    bf16_t* __restrict__ supt,        // [24][128][1024]
    float* __restrict__ tbuf)         // [8][128][1024]
{
    __shared__ bf16_t As[64*64];
    __shared__ bf16_t Bs[64*64];
    const int t = threadIdx.x, lane = t & 63, w = t >> 6;
    const int n0 = blockIdx.x * 64;
    const int m0 = blockIdx.y * 64;
    const int b  = blockIdx.z;
    const bf16_t* Arow = Wcat + (size_t)m0 * 384;
    const bf16_t* Brow = xcat + ((size_t)b * 1024 + n0) * 384;

    f32x4 acc[4] = {};
    for (int k0 = 0; k0 < 384; k0 += 64) {
        STAGE64(As, Bs, Arow, Brow, 384, 384, k0, w, lane);
        __syncthreads();
        MFMA64(As, Bs, acc, w, lane);
        __syncthreads();
    }
    #pragma unroll
    for (int j = 0; j < 4; ++j) {
        int n = n0 + j*16 + (lane & 15);
        #pragma unroll
        for (int rg = 0; rg < 4; ++rg) {
            int m = m0 + w*16 + (lane >> 4)*4 + rg;
            float v = acc[j][rg];
            if (m < 384) {
                int d = m >> 7, o = m & 127;
                supt[((size_t)((d*8 + b)*128 + o))*1024 + n] = (bf16_t)(v + Bcl[d*128 + o]);
            } else {
                int o = m - 384;
                tbuf[((size_t)(b*128 + o))*1024 + n] = fmaxf(v + Bhl[o], 0.0f);
            }
        }
    }
}

// ---------------------------------------------------------------------------
// colsum[row] = sum_n supt[row][n]  (row = z*128+o, 3072 rows), fp32.
// ---------------------------------------------------------------------------
__global__ __launch_bounds__(256) void k_colsum(
    const bf16_t* __restrict__ supt, float* __restrict__ colsum)
{
    int row = blockIdx.x * 4 + (threadIdx.x >> 6);
    int lane = threadIdx.x & 63;
    const bf16_t* p = supt + (size_t)row * 1024 + lane * 16;
    bf16x8 v0 = *reinterpret_cast<const bf16x8*>(p);
    bf16x8 v1 = *reinterpret_cast<const bf16x8*>(p + 8);
    float s = 0.0f;
    #pragma unroll
    for (int i = 0; i < 8; ++i) s += (float)v0[i] + (float)v1[i];
    #pragma unroll
    for (int off = 32; off > 0; off >>= 1) s += __shfl_down(s, off, 64);
    if (lane == 0) colsum[row] = s;
}

// ---------------------------------------------------------------------------
// k_gh (64x64): ghb[r][c] = bf16(sum_k' xcat[r][k'] * whhc[c][k'] + bhh[c])
// grid (128 m-tiles, 6 c-tiles). K'=384.
// ---------------------------------------------------------------------------
__global__ __launch_bounds__(256, 4) void k_gh(
    const bf16_t* __restrict__ A,     // [8192][384] (xcat flat)
    const bf16_t* __restrict__ B,     // [384][384]
    const float* __restrict__ bias,   // [384]
    bf16_t* __restrict__ C)           // [8192][384]
{
    __shared__ bf16_t As[64*64];
    __shared__ bf16_t Bs[64*64];
    const int t = threadIdx.x, lane = t & 63, w = t >> 6;
    const int m0 = blockIdx.x * 64;
    const int c0 = blockIdx.y * 64;
    const bf16_t* Arow = A + (size_t)m0 * 384;
    const bf16_t* Brow = B + (size_t)c0 * 384;

    f32x4 acc[4] = {};
    for (int k0 = 0; k0 < 384; k0 += 64) {
        STAGE64(As, Bs, Arow, Brow, 384, 384, k0, w, lane);
        __syncthreads();
        MFMA64(As, Bs, acc, w, lane);
        __syncthreads();
    }
    #pragma unroll
    for (int j = 0; j < 4; ++j) {
        int c = c0 + j*16 + (lane & 15);
        float bv = bias[c];
        #pragma unroll
        for (int rg = 0; rg < 4; ++rg) {
            int m = m0 + w*16 + (lane >> 4)*4 + rg;
            C[(size_t)m*G3 + c] = (bf16_t)(acc[j][rg] + bv);
        }
    }
}

// ---------------------------------------------------------------------------
// k_agg (64x64): agg[z][m][o] = sum_n adjc[z][m][n]*supt[z][o][n] + 0.5*colsum
// Output aggcat [24576][384] = [hi|lo|hi]. grid (16 m-tiles, 2 o-tiles, 24 z)
// ---------------------------------------------------------------------------
__global__ __launch_bounds__(256, 4) void k_agg(
    const bf16_t* __restrict__ adjb,   // [24][1024][1024] centered
    const bf16_t* __restrict__ supt,   // [24][128][1024]
    const float* __restrict__ colsum,  // [24][128]
    bf16_t* __restrict__ aggcat)       // [24576][384]
{
    __shared__ bf16_t As[64*64];
    __shared__ bf16_t Bs[64*64];
    const int t = threadIdx.x, lane = t & 63, w = t >> 6;
    const int m0 = blockIdx.x * 64;
    const int o0 = blockIdx.y * 64;
    const int z  = blockIdx.z;
    const bf16_t* Arow = adjb + (size_t)z * 1024 * 1024 + (size_t)m0 * 1024;
    const bf16_t* Brow = supt + (size_t)z * 128 * 1024 + (size_t)o0 * 1024;

    f32x4 acc[4] = {};
    for (int k0 = 0; k0 < 1024; k0 += 64) {
        STAGE64(As, Bs, Arow, Brow, 1024, 1024, k0, w, lane);
        __syncthreads();
        MFMA64(As, Bs, acc, w, lane);
        __syncthreads();
    }
    #pragma unroll
    for (int j = 0; j < 4; ++j) {
        int o = o0 + j*16 + (lane & 15);
        float cs = 0.5f * colsum[z*128 + o];
        #pragma unroll
        for (int rg = 0; rg < 4; ++rg) {
            size_t m = (size_t)z*1024 + m0 + w*16 + (lane >> 4)*4 + rg;
            float v = acc[j][rg] + cs;
            bf16_t hi = (bf16_t)v;
            bf16_t lo = (bf16_t)(v - (float)hi);
            bf16_t* row = aggcat + m*384;
            row[o] = hi; row[128 + o] = lo; row[256 + o] = hi;
        }
    }
}

// ---------------------------------------------------------------------------
// k_gi (64x64): gi[m][c] = sum_k' aggcat[m][k']*wihc[c][k'] + bih[c] (K'=384)
// c<256 -> girz bf16; c>=256 -> gin fp32. grid (384 m-tiles, 6 c-tiles).
// ---------------------------------------------------------------------------
__global__ __launch_bounds__(256, 4) void k_gi(
    const bf16_t* __restrict__ A,      // [24576][384]
    const bf16_t* __restrict__ B,      // [384][384]
    const float*  __restrict__ bias,   // [384]
    bf16_t* __restrict__ girz,         // [24576][256]
    float* __restrict__ gin)           // [24576][128]
{
    __shared__ bf16_t As[64*64];
    __shared__ bf16_t Bs[64*64];
    const int t = threadIdx.x, lane = t & 63, w = t >> 6;
    const int m0 = blockIdx.x * 64;
    const int c0 = blockIdx.y * 64;
    const bf16_t* Arow = A + (size_t)m0 * 384;
    const bf16_t* Brow = B + (size_t)c0 * 384;

    f32x4 acc[4] = {};
    for (int k0 = 0; k0 < 384; k0 += 64) {
        STAGE64(As, Bs, Arow, Brow, 384, 384, k0, w, lane);
        __syncthreads();
        MFMA64(As, Bs, acc, w, lane);
        __syncthreads();
    }
    #pragma unroll
    for (int j = 0; j < 4; ++j) {
        int c = c0 + j*16 + (lane & 15);
        float bv = bias[c];
        #pragma unroll
        for (int rg = 0; rg < 4; ++rg) {
            int m = m0 + w*16 + (lane >> 4)*4 + rg;
            float v = acc[j][rg] + bv;
            if (c < 256) girz[(size_t)m*256 + c] = (bf16_t)v;
            else         gin[(size_t)m*128 + (c - 256)] = v;
        }
    }
}

// ---------------------------------------------------------------------------
// GRU gates + sum over d + relu + highway blend.
// h reconstructed exactly from xcat (hi+lo). grid (64 n-blocks of 16, 8 b).
// ---------------------------------------------------------------------------
__global__ __launch_bounds__(256) void k_gates(
    const bf16_t* __restrict__ girz, const float* __restrict__ gin,
    const bf16_t* __restrict__ ghb,
    bf16_t* xcat,                       // NOT restrict: read+write same buffer
    const float* __restrict__ tbuf,
    float* __restrict__ Xout, int write_xcat)
{
    __shared__ float ts[128*17];
    const int b = blockIdx.y, n0 = blockIdx.x * 16;
    const int tid = threadIdx.x;
    {
        int o = tid >> 1, nh = (tid & 1) * 8;
        const float* src = tbuf + ((size_t)(b*128 + o))*1024 + n0 + nh;
        float4 v0 = *reinterpret_cast<const float4*>(src);
        float4 v1 = *reinterpret_cast<const float4*>(src + 4);
        float* dst = &ts[o*17 + nh];
        dst[0]=v0.x; dst[1]=v0.y; dst[2]=v0.z; dst[3]=v0.w;
        dst[4]=v1.x; dst[5]=v1.y; dst[6]=v1.z; dst[7]=v1.w;
    }
    __syncthreads();
    #pragma unroll
    for (int p = 0; p < 8; ++p) {
        int e = p*256 + tid;
        int nn = e >> 7, o = e & 127;
        int n = n0 + nn;
        size_t rb = (size_t)(b*1024 + n);
        bf16_t* xr = xcat + rb*384;
        float h = (float)xr[o] + (float)xr[256 + o];
        const bf16_t* ghr = ghb + rb*G3;
        float g_r = (float)ghr[o], g_z = (float)ghr[128+o], g_n = (float)ghr[256+o];
        float acc = 0.0f;
        #pragma unroll
        for (int d = 0; d < 3; ++d) {
            size_t rr = (size_t)((d*8 + b)*1024 + n);
            float i_r = (float)girz[rr*256 + o];
            float i_z = (float)girz[rr*256 + 128 + o];
            float i_n = gin[rr*128 + o];
            float rg = 1.0f / (1.0f + expf(-(i_r + g_r)));
            float zg = 1.0f / (1.0f + expf(-(i_z + g_z)));
            float ng = tanhf(i_n + rg * g_n);
            acc += (1.0f - zg) * ng + zg * h;
        }
        float outv = fmaxf(acc, 0.0f);
        float tg = ts[o*17 + nn];
        float res = outv * tg + h * (1.0f - tg);
        if (Xout) Xout[(size_t)(n*8 + b)*128 + o] = res;
        if (write_xcat) {
            bf16_t hi = (bf16_t)res;
            bf16_t lo = (bf16_t)(res - (float)hi);
            xr[o] = hi; xr[128 + o] = hi; xr[256 + o] = lo;
        }
    }
}

// ---------------------------------------------------------------------------
extern "C" void kernel_launch(void* const* d_in, const int* in_sizes, int n_in,
                              void* d_out, int out_size, void* d_ws, size_t ws_size,
                              hipStream_t stream) {
    const float* inputs = (const float*)d_in[0];   // [1024,8,128]
    const float* adj    = (const float*)d_in[1];   // [3,8,1024,1024]
    const float* W      = (const float*)d_in[2];   // [2,3,128,128]
    const float* Bc     = (const float*)d_in[3];   // [2,3,128]
    const float* Wh     = (const float*)d_in[4];   // [2,128,128]
    const float* Bh     = (const float*)d_in[5];   // [2,128]
    const float* Wih    = (const float*)d_in[6];   // [2,384,128]
    const float* Whh    = (const float*)d_in[7];   // [2,384,128]
    const float* bih    = (const float*)d_in[8];   // [2,384]
    const float* bhh    = (const float*)d_in[9];   // [2,384]

    char* ws = (char*)d_ws;
    float*  tbuf   = (float*)ws;   ws += (size_t)8*128*1024*4;      // 4.19 MB
    bf16_t* xcat   = (bf16_t*)ws;  ws += (size_t)8*1024*384*2;      // 6.29 MB
    bf16_t* ghb    = (bf16_t*)ws;  ws += (size_t)NB*G3*2;           // 6.29 MB
    bf16_t* supt   = (bf16_t*)ws;  ws += (size_t)24*128*1024*2;     // 6.29 MB
    bf16_t* aggcat = (bf16_t*)ws;  ws += (size_t)3*NB*384*2;        // 18.87 MB
    bf16_t* girz   = (bf16_t*)ws;  ws += (size_t)3*NB*256*2;        // 12.58 MB
    float*  gin    = (float*)ws;   ws += (size_t)3*NB*128*4;        // 12.58 MB
    float*  colsum = (float*)ws;   ws += (size_t)24*128*4;          // 12 KB
    bf16_t* wsup   = (bf16_t*)ws;  ws += (size_t)2*512*384*2;       // 0.79 MB
    bf16_t* whhc   = (bf16_t*)ws;  ws += (size_t)2*384*384*2;       // 1.18 MB
    bf16_t* wihc   = (bf16_t*)ws;  ws += (size_t)2*384*384*2;       // 1.18 MB
    bf16_t* adjb   = (bf16_t*)ws;                                   // 50.33 MB

    // one-time preps
    k_cvt_adj<<<dim3(4096), dim3(256), 0, stream>>>(adj, adjb, 3*8*1024*1024/4);
    k_wprep<<<dim3(1280, 2), dim3(128), 0, stream>>>(W, Wh, Whh, Wih, wsup, whhc, wihc);
    k_xcat<<<dim3(4096), dim3(256), 0, stream>>>(inputs, xcat);

    for (int l = 0; l < 2; ++l) {
        // support (bf16 [z][o][n]) + highway t (fp32 [b][o][n])
        k_sup<<<dim3(16, 8, 8), dim3(256), 0, stream>>>(
            wsup + (size_t)l*512*384, xcat, Bc + l*3*128, Bh + l*128, supt, tbuf);
        // column sums of support (for centered-adj correction)
        k_colsum<<<dim3(768), dim3(256), 0, stream>>>(supt, colsum);
        // gh = x @ Whh^T + bhh
        k_gh<<<dim3(128, 6), dim3(256), 0, stream>>>(
            xcat, whhc + (size_t)l*384*384, bhh + l*G3, ghb);
        // agg = adjc @ support + 0.5*colsum, output hi/lo-cat
        k_agg<<<dim3(16, 2, 24), dim3(256), 0, stream>>>(adjb, supt, colsum, aggcat);
        // gi = agg @ Wih^T + bih (K'=384)
        k_gi<<<dim3(384, 6), dim3(256), 0, stream>>>(
            aggcat, wihc + (size_t)l*384*384, bih + l*G3, girz, gin);
        // gates + sum_d + relu + highway; layer0 -> xcat update, layer1 -> d_out
        k_gates<<<dim3(64, 8), dim3(256), 0, stream>>>(
            girz, gin, ghb, xcat, tbuf,
            (l == 1) ? (float*)d_out : (float*)nullptr, (l == 0) ? 1 : 0);
    }
}